// Round 16
// baseline (1496.919 us; speedup 1.0000x reference)
//
#include <hip/hip_runtime.h>
#include <hip/hip_fp16.h>

#define DD 32
#define NLAYERS 8
#define TOPK 8

typedef _Float16 half8 __attribute__((ext_vector_type(8)));
typedef __fp16 half2v __attribute__((ext_vector_type(2)));
typedef float f32x4 __attribute__((ext_vector_type(4)));

__device__ __forceinline__ unsigned encf(float x){ unsigned u=__float_as_uint(x); return (u&0x80000000u)? ~u : (u|0x80000000u); }
__device__ __forceinline__ unsigned short f2h(float f){ return __half_as_ushort(__float2half(f)); }
__device__ __forceinline__ float h2f(unsigned short u){ return __half2float(__ushort_as_half(u)); }
__device__ __forceinline__ half2v u2h2(unsigned u){ union {unsigned u; half2v h;} c; c.u=u; return c.h; }
__device__ __forceinline__ unsigned h22u(half2v h){ union {unsigned u; half2v h;} c; c.h=h; return c.u; }
__device__ __forceinline__ int gidx(const void* p, long i, int i64){
  return i64 ? (int)((const long long*)p)[i] : ((const int*)p)[i];
}

__global__ void k_detect(const int* __restrict__ srcw, int* __restrict__ iflag){
  if (threadIdx.x==0 && blockIdx.x==0){
    int allz = 1;
    for (int k=1;k<32;k+=2) if (srcw[k]!=0) allz = 0;
    *iflag = allz;
  }
}

__global__ void k_zero(int* cnt, int* cursor, int N){
  int n = blockIdx.x*blockDim.x + threadIdx.x;
  if (n<N){ cnt[n]=0; cursor[n]=0; }
}

// h16 = fp16(relu(tok_emb[h_tok])) ; in-degree histogram
__global__ void k_init(const void* __restrict__ h_tok, const void* __restrict__ dstv,
                       const float* __restrict__ tok_emb,
                       unsigned short* __restrict__ h16, int* __restrict__ cnt,
                       const int* __restrict__ iflag, int N, int E)
{
  int i64 = *iflag;
  long idx = (long)blockIdx.x*blockDim.x + threadIdx.x;
  if (idx < (long)N*8){
    int n=(int)(idx>>3), q=(int)(idx&7);
    int t = gidx(h_tok, n, i64);
    float4 v = reinterpret_cast<const float4*>(tok_emb)[t*8+q];
    uint2 o;
    o.x = (unsigned)f2h(fmaxf(v.x,0.f)) | ((unsigned)f2h(fmaxf(v.y,0.f))<<16);
    o.y = (unsigned)f2h(fmaxf(v.z,0.f)) | ((unsigned)f2h(fmaxf(v.w,0.f))<<16);
    reinterpret_cast<uint2*>(h16)[(long)n*8+q] = o;
    return;
  }
  idx -= (long)N*8;
  if (idx < E){
    atomicAdd(&cnt[gidx(dstv, idx, i64)], 1);
  }
}

// single-block exclusive scan of in-degrees -> csr_off (wave shuffle-scan)
__global__ __launch_bounds__(1024) void k_scan(const int* __restrict__ cnt, int* __restrict__ off,
                                               int N, int E){
  __shared__ int wsum[16];
  __shared__ int carry_s;
  int tid = threadIdx.x;
  int lane = tid & 63, w = tid >> 6;
  if (tid==0) carry_s = 0;
  __syncthreads();
  for (int base=0; base<N; base+=1024){
    int v = (base+tid<N)? cnt[base+tid] : 0;
    int x = v;
    #pragma unroll
    for (int d=1; d<64; d<<=1){
      int t = __shfl_up(x, d, 64);
      if (lane>=d) x += t;
    }
    if (lane==63) wsum[w] = x;
    __syncthreads();
    if (w==0 && lane<16){
      int y = wsum[lane];
      #pragma unroll
      for (int d=1; d<16; d<<=1){
        int t = __shfl_up(y, d, 64);
        if (lane>=d) y += t;
      }
      wsum[lane] = y;
    }
    __syncthreads();
    int cl = carry_s;
    int wb = (w>0)? wsum[w-1] : 0;
    int tot = wsum[15];
    if (base+tid<N) off[base+tid] = cl + x + wb - v;
    __syncthreads();
    if (tid==0) carry_s = cl + tot;
    __syncthreads();
  }
  if (tid==0) off[N] = E;
}

// CSR positions: ONE 8-B scatter per edge (sd + edge id in a single uint2)
__global__ void k_scatter(const void* __restrict__ srcv, const void* __restrict__ dstv,
                          const int* __restrict__ off, int* __restrict__ cursor,
                          uint2* __restrict__ sde8,
                          const int* __restrict__ iflag, int E){
  int i64 = *iflag;
  int e = blockIdx.x*blockDim.x + threadIdx.x;
  if (e>=E) return;
  int d = gidx(dstv, e, i64), s = gidx(srcv, e, i64);
  int pos = off[d] + atomicAdd(&cursor[d],1);
  uint2 r; r.x = ((unsigned)d<<16) | (unsigned)s; r.y = (unsigned)e;
  sde8[pos] = r;
}

// stream sde8: emit csr_sd sequentially + fill ebuf from L1-resident e_emb table
__global__ void k_fill(const uint2* __restrict__ sde8, const void* __restrict__ e_tok,
                       const float* __restrict__ e_emb,
                       unsigned* __restrict__ csr_sd, unsigned short* __restrict__ ebuf,
                       const int* __restrict__ iflag, int E){
  int i64 = *iflag;
  long idx = (long)blockIdx.x*blockDim.x + threadIdx.x;
  if (idx >= (long)E*4) return;
  int pos = (int)(idx>>2), j = (int)(idx&3);
  uint2 r = sde8[pos];
  if (j==0) csr_sd[pos] = r.x;
  int t = gidx(e_tok, (int)r.y, i64);
  const float4* sp = reinterpret_cast<const float4*>(e_emb + t*DD) + j*2;
  float4 x = sp[0], y = sp[1];
  uint4 ov;
  ov.x = (unsigned)f2h(x.x) | ((unsigned)f2h(x.y)<<16);
  ov.y = (unsigned)f2h(x.z) | ((unsigned)f2h(x.w)<<16);
  ov.z = (unsigned)f2h(y.x) | ((unsigned)f2h(y.y)<<16);
  ov.w = (unsigned)f2h(y.z) | ((unsigned)f2h(y.w)<<16);
  reinterpret_cast<uint4*>(ebuf)[(long)pos*4+j] = ov;
}

// hA16=h16@Wni, hB16=h16@Wnj   (first layer only)
__global__ __launch_bounds__(256) void k_nodeAB(
    const unsigned short* __restrict__ h16,
    const float* __restrict__ WA, const float* __restrict__ WB,
    unsigned short* __restrict__ hA16, unsigned short* __restrict__ hB16, int N)
{
  __shared__ float hl[8][DD];
  int tid = threadIdx.x;
  int ln = tid>>5, c = tid&31;
  int n = blockIdx.x*8 + ln;
  hl[ln][c] = (n<N)? h2f(h16[(long)n*DD+c]) : 0.f;
  __syncthreads();
  float a=0.f,b=0.f;
  #pragma unroll
  for (int k=0;k<DD;k++){
    float v = hl[ln][k];
    a = fmaf(v, WA[k*DD+c], a);
    b = fmaf(v, WB[k*DD+c], b);
  }
  if (n<N){ hA16[(long)n*DD+c]=f2h(a); hB16[(long)n*DD+c]=f2h(b); }
}

// MFMA edge kernel, SOFTWARE-PIPELINED (depth 1): one wave = 16 edges.
// D[m][n=edge]=Wf^T·e^T; f=leaky(D+hA[src]+hB[dst]+b); ebuf<-f; lbuf=exp(f·attn)
__global__ __launch_bounds__(256) void k_edge(
    unsigned short* __restrict__ ebuf,
    const unsigned short* __restrict__ hA16, const unsigned short* __restrict__ hB16,
    const unsigned* __restrict__ csr_sd,
    const float* __restrict__ Wf, const float* __restrict__ bvec,
    const float* __restrict__ attn,
    unsigned short* __restrict__ lbuf, int ntiles, int writef)
{
  int lane = threadIdx.x & 63;
  int wid = (blockIdx.x*256 + threadIdx.x) >> 6;
  int nw  = (gridDim.x*256) >> 6;
  int m = lane & 15, q = lane >> 4;
  half8 a0, a1;
  #pragma unroll
  for (int j=0;j<8;j++){
    a0[j] = (_Float16)Wf[(q*8+j)*DD + m];
    a1[j] = (_Float16)Wf[(q*8+j)*DD + 16 + m];
  }
  half2v bh[4], ah[4];
  #pragma unroll
  for (int j=0;j<2;j++){
    bh[j]   = __builtin_amdgcn_cvt_pkrtz(bvec[q*4+2*j],    bvec[q*4+2*j+1]);
    bh[2+j] = __builtin_amdgcn_cvt_pkrtz(bvec[16+q*4+2*j], bvec[16+q*4+2*j+1]);
    ah[j]   = __builtin_amdgcn_cvt_pkrtz(attn[q*4+2*j],    attn[q*4+2*j+1]);
    ah[2+j] = __builtin_amdgcn_cvt_pkrtz(attn[16+q*4+2*j], attn[16+q*4+2*j+1]);
  }
  const half2v c001 = {(__fp16)0.01f, (__fp16)0.01f};
  f32x4 zero = {0.f,0.f,0.f,0.f};
  // pipeline preamble: load tile wid fully
  half8 b_c = {};
  unsigned sd_c = 0;
  uint2 uA0_c={0,0}, uA1_c={0,0}, uB0_c={0,0}, uB1_c={0,0};
  if (wid < ntiles){
    long e0 = (long)wid*16 + m;
    sd_c = csr_sd[e0];
    b_c = *reinterpret_cast<const half8*>(ebuf + e0*DD + q*8);
    unsigned s = sd_c & 0xFFFFu, d = sd_c >> 16;
    const uint2* pA = reinterpret_cast<const uint2*>(hA16 + (long)s*DD);
    const uint2* pB = reinterpret_cast<const uint2*>(hB16 + (long)d*DD);
    uA0_c=pA[q]; uA1_c=pA[4+q]; uB0_c=pB[q]; uB1_c=pB[4+q];
  }
  for (int t = wid; t < ntiles; t += nw){
    int tn = t + nw;
    // 1) issue next tile's sd + b (no deps; outstanding through this tile's MFMA)
    unsigned sd_n = 0; half8 b_n = {};
    if (tn < ntiles){
      long en = (long)tn*16 + m;
      sd_n = csr_sd[en];
      b_n = *reinterpret_cast<const half8*>(ebuf + en*DD + q*8);
    }
    // 2) MFMA on current tile (hides sd_n latency)
    f32x4 d0 = __builtin_amdgcn_mfma_f32_16x16x32_f16(a0, b_c, zero, 0,0,0);
    f32x4 d1 = __builtin_amdgcn_mfma_f32_16x16x32_f16(a1, b_c, zero, 0,0,0);
    // 3) issue next tile's gathers (hidden by epilogue + stores + next MFMA)
    uint2 uA0_n={0,0}, uA1_n={0,0}, uB0_n={0,0}, uB1_n={0,0};
    if (tn < ntiles){
      unsigned s = sd_n & 0xFFFFu, d = sd_n >> 16;
      const uint2* pA = reinterpret_cast<const uint2*>(hA16 + (long)s*DD);
      const uint2* pB = reinterpret_cast<const uint2*>(hB16 + (long)d*DD);
      uA0_n=pA[q]; uA1_n=pA[4+q]; uB0_n=pB[q]; uB1_n=pB[4+q];
    }
    // 4) epilogue with current gathers
    long tbase = (long)t*16;
    long edge = tbase + m;
    half2v D[4];
    D[0] = __builtin_amdgcn_cvt_pkrtz(d0[0], d0[1]);
    D[1] = __builtin_amdgcn_cvt_pkrtz(d0[2], d0[3]);
    D[2] = __builtin_amdgcn_cvt_pkrtz(d1[0], d1[1]);
    D[3] = __builtin_amdgcn_cvt_pkrtz(d1[2], d1[3]);
    half2v A[4] = {u2h2(uA0_c.x), u2h2(uA0_c.y), u2h2(uA1_c.x), u2h2(uA1_c.y)};
    half2v B[4] = {u2h2(uB0_c.x), u2h2(uB0_c.y), u2h2(uB1_c.x), u2h2(uB1_c.y)};
    float l = 0.f;
    half2v F[4];
    #pragma unroll
    for (int j=0;j<4;j++){
      half2v f = D[j] + A[j] + B[j] + bh[j];             // v_pk_add_f16
      f = __builtin_elementwise_max(f, f*c001);          // leaky
      F[j] = f;
      l = __builtin_amdgcn_fdot2(f, ah[j], l, false);    // v_dot2_f32_f16
    }
    if (writef){
      uint2 w0, w1;
      w0.x = h22u(F[0]); w0.y = h22u(F[1]);
      w1.x = h22u(F[2]); w1.y = h22u(F[3]);
      *reinterpret_cast<uint2*>(ebuf + edge*DD + q*4) = w0;
      *reinterpret_cast<uint2*>(ebuf + edge*DD + 16 + q*4) = w1;
    }
    l += __shfl_xor(l, 16, 64);
    l += __shfl_xor(l, 32, 64);
    if (lane < 16){
      float lc = fminf(fmaxf(l, -15.f), 10.5f);
      lbuf[tbase + lane] = f2h(__expf(lc));   // max-free softmax weight
    }
    // rotate pipeline
    sd_c = sd_n; b_c = b_n;
    uA0_c=uA0_n; uA1_c=uA1_n; uB0_c=uB0_n; uB1_c=uB1_n;
  }
}

// FUSED aggr + proj + nodeAB(next layer): reads h16i, writes h16o/hA16/hB16
__global__ __launch_bounds__(256) void k_aggrp(
    const unsigned short* __restrict__ h16i, const unsigned short* __restrict__ lbuf,
    const int* __restrict__ off, const unsigned* __restrict__ csr_sd,
    const float* __restrict__ Wnd, const float* __restrict__ WA, const float* __restrict__ WB,
    unsigned short* __restrict__ h16o,
    unsigned short* __restrict__ hA16, unsigned short* __restrict__ hB16, int N)
{
  __shared__ float gl[8][DD];
  __shared__ float tl[8][DD];
  int tid = threadIdx.x;
  int ln = tid>>5, c = tid&31;
  int n = blockIdx.x*8 + ln;
  float g = 0.f;
  if (n<N){
    int o0 = off[n], o1 = off[n+1];
    float num=0.f, den=0.f;
    for (int i=o0;i<o1;i++){
      float ex = h2f(lbuf[i]);
      unsigned s = csr_sd[i] & 0xFFFFu;
      num = fmaf(ex, h2f(h16i[(long)s*DD+c]), num);
      den += ex;
    }
    g = (den>0.f) ? num/den : 0.f;
  }
  gl[ln][c] = g;
  __syncthreads();
  float t=0.f;
  #pragma unroll
  for (int k=0;k<DD;k++) t = fmaf(gl[ln][k], Wnd[k*DD+c], t);
  t = fmaxf(t, 0.f);
  tl[ln][c] = t;
  __syncthreads();
  float a=0.f,b=0.f;
  #pragma unroll
  for (int k=0;k<DD;k++){
    float v = tl[ln][k];
    a = fmaf(v, WA[k*DD+c], a);
    b = fmaf(v, WB[k*DD+c], b);
  }
  if (n<N){
    h16o[(long)n*DD+c]=f2h(t);
    hA16[(long)n*DD+c]=f2h(a);
    hB16[(long)n*DD+c]=f2h(b);
  }
}

// FUSED aggr + final proj: h(fp32) = relu(g @ Wnode)
__global__ __launch_bounds__(256) void k_aggrF(
    const unsigned short* __restrict__ h16i, const unsigned short* __restrict__ lbuf,
    const int* __restrict__ off, const unsigned* __restrict__ csr_sd,
    const float* __restrict__ Wnd, float* __restrict__ h, int N)
{
  __shared__ float gl[8][DD];
  int tid = threadIdx.x;
  int ln = tid>>5, c = tid&31;
  int n = blockIdx.x*8 + ln;
  float g = 0.f;
  if (n<N){
    int o0 = off[n], o1 = off[n+1];
    float num=0.f, den=0.f;
    for (int i=o0;i<o1;i++){
      float ex = h2f(lbuf[i]);
      unsigned s = csr_sd[i] & 0xFFFFu;
      num = fmaf(ex, h2f(h16i[(long)s*DD+c]), num);
      den += ex;
    }
    g = (den>0.f) ? num/den : 0.f;
  }
  gl[ln][c] = g;
  __syncthreads();
  float t=0.f;
  #pragma unroll
  for (int k=0;k<DD;k++) t = fmaf(gl[ln][k], Wnd[k*DD+c], t);
  if (n<N) h[(long)n*DD+c] = fmaxf(t, 0.f);
}

__global__ void k_keys(const float* __restrict__ h, unsigned long long* __restrict__ keys, int N){
  int n = blockIdx.x*blockDim.x + threadIdx.x;
  if (n>=N) return;
  const float4* p = reinterpret_cast<const float4*>(h + (long)n*DD);
  float m = -1e38f;
  #pragma unroll
  for (int j=0;j<8;j++){
    float4 v = p[j];
    m = fmaxf(m, fmaxf(fmaxf(v.x,v.y), fmaxf(v.z,v.w)));
  }
  keys[n] = ((unsigned long long)encf(m)<<32) | (unsigned)(~(unsigned)n);
}

// parallel top-8: per-thread register top-8 + 8-round block tournament (keys unique)
__global__ __launch_bounds__(256) void k_ptop(const unsigned long long* __restrict__ keys, int N,
                                              unsigned long long* __restrict__ outk){
  __shared__ unsigned long long red[256];
  int tid = threadIdx.x, b = blockIdx.x, nb = gridDim.x;
  int chunk = (N + nb - 1) / nb;
  int base = b*chunk, end = base+chunk; if (end>N) end=N;
  unsigned long long loc[TOPK];
  #pragma unroll
  for (int i=0;i<TOPK;i++) loc[i]=0ull;
  for (int i=base+tid; i<end; i+=256){
    unsigned long long k = keys[i];
    if (k > loc[TOPK-1]){
      int j = TOPK-1;
      while (j>0 && loc[j-1]<k){ loc[j]=loc[j-1]; j--; }
      loc[j]=k;
    }
  }
  for (int r=0; r<TOPK; r++){
    red[tid] = loc[0];
    __syncthreads();
    for (int s=128; s>0; s>>=1){
      if (tid<s && red[tid+s]>red[tid]) red[tid]=red[tid+s];
      __syncthreads();
    }
    unsigned long long w = red[0];
    if (tid==0) outk[b*TOPK + r] = w;
    if (loc[0]==w){
      #pragma unroll
      for (int j=0;j<TOPK-1;j++) loc[j]=loc[j+1];
      loc[TOPK-1]=0ull;
    }
    __syncthreads();
  }
}

__global__ __launch_bounds__(256) void k_head(
    const float* __restrict__ h, const unsigned long long* __restrict__ sel,
    const float* __restrict__ Wlin, const float* __restrict__ blin,
    const float* __restrict__ W1, const float* __restrict__ b1,
    const float* __restrict__ W2, const float* __restrict__ b2,
    const float* __restrict__ Wc, const float* __restrict__ bc,
    float* __restrict__ out, int N)
{
  __shared__ float xs[TOPK][DD];
  __shared__ float y1[DD], y2[DD], y3[DD];
  int tid=threadIdx.x;
  int r=tid>>5, c=tid&31;
  unsigned node = ~(unsigned)(sel[r] & 0xFFFFFFFFull);
  if (node >= (unsigned)N) node = 0;
  xs[r][c] = h[(long)node*DD + c];
  __syncthreads();
  if (tid<TOPK){
    for (int i=1;i<DD;i++){
      float v=xs[tid][i]; int j=i-1;
      while (j>=0 && xs[tid][j]>v){ xs[tid][j+1]=xs[tid][j]; j--; }
      xs[tid][j+1]=v;
    }
  }
  __syncthreads();
  if (tid<DD){
    float a=blin[tid];
    for (int i=0;i<TOPK*DD;i++) a = fmaf(xs[i>>5][i&31], Wlin[i*DD+tid], a);
    y1[tid] = a>0.f? a : 0.f;
  }
  __syncthreads();
  if (tid<DD){
    float a=b1[tid];
    #pragma unroll
    for (int i=0;i<DD;i++) a = fmaf(y1[i], W1[i*DD+tid], a);
    y2[tid] = a>0.f? a : 0.f;
  }
  __syncthreads();
  if (tid<DD){
    float a=b2[tid];
    #pragma unroll
    for (int i=0;i<DD;i++) a = fmaf(y2[i], W2[i*DD+tid], a);
    y3[tid] = a>0.f? a : 0.f;
  }
  __syncthreads();
  if (tid<2){
    float a=bc[tid];
    #pragma unroll
    for (int i=0;i<DD;i++) a = fmaf(y3[i], Wc[i*2+tid], a);
    out[tid] = a;                       // fp32 output
  }
}

extern "C" void kernel_launch(void* const* d_in, const int* in_sizes, int n_in,
                              void* d_out, int out_size, void* d_ws, size_t ws_size,
                              hipStream_t stream) {
  const int N = in_sizes[0];
  const int E = in_sizes[1];
  const float* tok_emb   = (const float*)d_in[4];
  const float* e_tok_emb = (const float*)d_in[5];
  const float* W_ni  = (const float*)d_in[6];
  const float* W_nj  = (const float*)d_in[7];
  const float* W_fij = (const float*)d_in[8];
  const float* b_e   = (const float*)d_in[9];
  const float* attn  = (const float*)d_in[10];
  const float* W_nd  = (const float*)d_in[11];

  char* p = (char*)d_ws;
  auto alloc = [&](size_t bytes)->char* {
    char* r = p; p += (bytes + 255) & ~(size_t)255; return r;
  };
  // ~131.5 MB total (sde8 aliases h+h16b+lbuf, all dead at setup)
  int* iflag = (int*)alloc(256);
  unsigned long long* sel = (unsigned long long*)alloc(256);
  unsigned long long* cand = (unsigned long long*)alloc(256*TOPK*8);
  int* csroff = (int*)alloc((size_t)(N+1)*4);
  unsigned* csr_sd = (unsigned*)alloc((size_t)(E+16)*4);
  float* h = (float*)alloc((size_t)N*DD*4);                     // fp32, final only
  unsigned short* h16b = (unsigned short*)alloc((size_t)N*DD*2);
  unsigned short* lbuf = (unsigned short*)alloc((size_t)(E+16)*2);
  unsigned short* h16a = (unsigned short*)alloc((size_t)N*DD*2);
  unsigned short* hA16 = (unsigned short*)alloc((size_t)N*DD*2);
  unsigned short* hB16 = (unsigned short*)alloc((size_t)N*DD*2);
  unsigned short* ebuf = (unsigned short*)alloc((size_t)(E+16)*DD*2);
  int* cnt    = (int*)hA16;                       // alias: dead until nodeAB
  int* cursor = (int*)hB16;                       // alias: dead until nodeAB
  uint2* sde8 = (uint2*)h;                        // alias: spans h+h16b+lbuf (12.8 MB)
  unsigned long long* keys = (unsigned long long*)lbuf;  // alias: lbuf dead after aggrF

  hipLaunchKernelGGL(k_detect, dim3(1), dim3(64), 0, stream, (const int*)d_in[2], iflag);
  hipLaunchKernelGGL(k_zero, dim3((N+255)/256), dim3(256), 0, stream, cnt, cursor, N);
  {
    long total = (long)N*8 + E;
    hipLaunchKernelGGL(k_init, dim3((int)((total+255)/256)), dim3(256), 0, stream,
                       d_in[0], d_in[3], tok_emb, h16a, cnt, iflag, N, E);
  }
  hipLaunchKernelGGL(k_scan, dim3(1), dim3(1024), 0, stream, cnt, csroff, N, E);
  hipLaunchKernelGGL(k_scatter, dim3((E+255)/256), dim3(256), 0, stream,
                     d_in[2], d_in[3], csroff, cursor, sde8, iflag, E);
  hipLaunchKernelGGL(k_fill, dim3((int)(((long)E*4+255)/256)), dim3(256), 0, stream,
                     sde8, d_in[1], e_tok_emb, csr_sd, ebuf, iflag, E);

  int nb_node = (N+7)/8;
  int ntiles = (E+15)/16;
  hipLaunchKernelGGL(k_nodeAB, dim3(nb_node), dim3(256), 0, stream,
                     h16a, W_ni, W_nj, hA16, hB16, N);
  unsigned short* hcur = h16a;
  unsigned short* hnxt = h16b;
  for (int l=0; l<NLAYERS; l++){
    const float* Wf  = W_fij + (size_t)l*DD*DD;
    const float* bl  = b_e   + (size_t)l*DD;
    const float* at  = attn  + (size_t)l*DD;
    const float* Wnd = W_nd  + (size_t)l*DD*DD;
    hipLaunchKernelGGL(k_edge, dim3(2048), dim3(256), 0, stream,
                       ebuf, hA16, hB16, csr_sd, Wf, bl, at, lbuf, ntiles,
                       (l < NLAYERS-1) ? 1 : 0);
    if (l < NLAYERS-1){
      const float* WnA = W_ni + (size_t)(l+1)*DD*DD;
      const float* WnB = W_nj + (size_t)(l+1)*DD*DD;
      hipLaunchKernelGGL(k_aggrp, dim3(nb_node), dim3(256), 0, stream,
                         hcur, lbuf, csroff, csr_sd, Wnd, WnA, WnB,
                         hnxt, hA16, hB16, N);
      unsigned short* tmp = hcur; hcur = hnxt; hnxt = tmp;
    } else {
      hipLaunchKernelGGL(k_aggrF, dim3(nb_node), dim3(256), 0, stream,
                         hcur, lbuf, csroff, csr_sd, Wnd, h, N);
    }
  }

  hipLaunchKernelGGL(k_keys, dim3((N+255)/256), dim3(256), 0, stream, h, keys, N);
  hipLaunchKernelGGL(k_ptop, dim3(256), dim3(256), 0, stream, keys, N, cand);
  hipLaunchKernelGGL(k_ptop, dim3(1), dim3(256), 0, stream, cand, 256*TOPK, sel);
  hipLaunchKernelGGL(k_head, dim3(1), dim3(256), 0, stream,
                     h, sel,
                     (const float*)d_in[12], (const float*)d_in[13],
                     (const float*)d_in[14], (const float*)d_in[15],
                     (const float*)d_in[16], (const float*)d_in[17],
                     (const float*)d_in[18], (const float*)d_in[19],
                     (float*)d_out, N);
}

// Round 17
// 1425.147 us; speedup vs baseline: 1.0504x; 1.0504x over previous
//
#include <hip/hip_runtime.h>
#include <hip/hip_fp16.h>

#define DD 32
#define NLAYERS 8
#define TOPK 8

typedef _Float16 half8 __attribute__((ext_vector_type(8)));
typedef __fp16 half2v __attribute__((ext_vector_type(2)));
typedef float f32x4 __attribute__((ext_vector_type(4)));

__device__ __forceinline__ unsigned encf(float x){ unsigned u=__float_as_uint(x); return (u&0x80000000u)? ~u : (u|0x80000000u); }
__device__ __forceinline__ unsigned short f2h(float f){ return __half_as_ushort(__float2half(f)); }
__device__ __forceinline__ float h2f(unsigned short u){ return __half2float(__ushort_as_half(u)); }
__device__ __forceinline__ half2v u2h2(unsigned u){ union {unsigned u; half2v h;} c; c.u=u; return c.h; }
__device__ __forceinline__ unsigned h22u(half2v h){ union {unsigned u; half2v h;} c; c.h=h; return c.u; }
__device__ __forceinline__ int gidx(const void* p, long i, int i64){
  return i64 ? (int)((const long long*)p)[i] : ((const int*)p)[i];
}

__global__ void k_detect(const int* __restrict__ srcw, int* __restrict__ iflag){
  if (threadIdx.x==0 && blockIdx.x==0){
    int allz = 1;
    for (int k=1;k<32;k+=2) if (srcw[k]!=0) allz = 0;
    *iflag = allz;
  }
}

__global__ void k_zero(int* cnt, int* cursor, int N){
  int n = blockIdx.x*blockDim.x + threadIdx.x;
  if (n<N){ cnt[n]=0; cursor[n]=0; }
}

// h16 = fp16(relu(tok_emb[h_tok])) ; in-degree histogram
__global__ void k_init(const void* __restrict__ h_tok, const void* __restrict__ dstv,
                       const float* __restrict__ tok_emb,
                       unsigned short* __restrict__ h16, int* __restrict__ cnt,
                       const int* __restrict__ iflag, int N, int E)
{
  int i64 = *iflag;
  long idx = (long)blockIdx.x*blockDim.x + threadIdx.x;
  if (idx < (long)N*8){
    int n=(int)(idx>>3), q=(int)(idx&7);
    int t = gidx(h_tok, n, i64);
    float4 v = reinterpret_cast<const float4*>(tok_emb)[t*8+q];
    uint2 o;
    o.x = (unsigned)f2h(fmaxf(v.x,0.f)) | ((unsigned)f2h(fmaxf(v.y,0.f))<<16);
    o.y = (unsigned)f2h(fmaxf(v.z,0.f)) | ((unsigned)f2h(fmaxf(v.w,0.f))<<16);
    reinterpret_cast<uint2*>(h16)[(long)n*8+q] = o;
    return;
  }
  idx -= (long)N*8;
  if (idx < E){
    atomicAdd(&cnt[gidx(dstv, idx, i64)], 1);
  }
}

// single-block exclusive scan of in-degrees -> csr_off (wave shuffle-scan)
__global__ __launch_bounds__(1024) void k_scan(const int* __restrict__ cnt, int* __restrict__ off,
                                               int N, int E){
  __shared__ int wsum[16];
  __shared__ int carry_s;
  int tid = threadIdx.x;
  int lane = tid & 63, w = tid >> 6;
  if (tid==0) carry_s = 0;
  __syncthreads();
  for (int base=0; base<N; base+=1024){
    int v = (base+tid<N)? cnt[base+tid] : 0;
    int x = v;
    #pragma unroll
    for (int d=1; d<64; d<<=1){
      int t = __shfl_up(x, d, 64);
      if (lane>=d) x += t;
    }
    if (lane==63) wsum[w] = x;
    __syncthreads();
    if (w==0 && lane<16){
      int y = wsum[lane];
      #pragma unroll
      for (int d=1; d<16; d<<=1){
        int t = __shfl_up(y, d, 64);
        if (lane>=d) y += t;
      }
      wsum[lane] = y;
    }
    __syncthreads();
    int cl = carry_s;
    int wb = (w>0)? wsum[w-1] : 0;
    int tot = wsum[15];
    if (base+tid<N) off[base+tid] = cl + x + wb - v;
    __syncthreads();
    if (tid==0) carry_s = cl + tot;
    __syncthreads();
  }
  if (tid==0) off[N] = E;
}

// CSR positions: ONE 8-B scatter per edge (sd + edge id in a single uint2)
__global__ void k_scatter(const void* __restrict__ srcv, const void* __restrict__ dstv,
                          const int* __restrict__ off, int* __restrict__ cursor,
                          uint2* __restrict__ sde8,
                          const int* __restrict__ iflag, int E){
  int i64 = *iflag;
  int e = blockIdx.x*blockDim.x + threadIdx.x;
  if (e>=E) return;
  int d = gidx(dstv, e, i64), s = gidx(srcv, e, i64);
  int pos = off[d] + atomicAdd(&cursor[d],1);
  uint2 r; r.x = ((unsigned)d<<16) | (unsigned)s; r.y = (unsigned)e;
  sde8[pos] = r;
}

// stream sde8: emit csr_sd sequentially + fill ebuf from L1-resident e_emb table
__global__ void k_fill(const uint2* __restrict__ sde8, const void* __restrict__ e_tok,
                       const float* __restrict__ e_emb,
                       unsigned* __restrict__ csr_sd, unsigned short* __restrict__ ebuf,
                       const int* __restrict__ iflag, int E){
  int i64 = *iflag;
  long idx = (long)blockIdx.x*blockDim.x + threadIdx.x;
  if (idx >= (long)E*4) return;
  int pos = (int)(idx>>2), j = (int)(idx&3);
  uint2 r = sde8[pos];
  if (j==0) csr_sd[pos] = r.x;
  int t = gidx(e_tok, (int)r.y, i64);
  const float4* sp = reinterpret_cast<const float4*>(e_emb + t*DD) + j*2;
  float4 x = sp[0], y = sp[1];
  uint4 ov;
  ov.x = (unsigned)f2h(x.x) | ((unsigned)f2h(x.y)<<16);
  ov.y = (unsigned)f2h(x.z) | ((unsigned)f2h(x.w)<<16);
  ov.z = (unsigned)f2h(y.x) | ((unsigned)f2h(y.y)<<16);
  ov.w = (unsigned)f2h(y.z) | ((unsigned)f2h(y.w)<<16);
  reinterpret_cast<uint4*>(ebuf)[(long)pos*4+j] = ov;
}

// hA16=h16@Wni, hB16=h16@Wnj   (first layer only)
__global__ __launch_bounds__(256) void k_nodeAB(
    const unsigned short* __restrict__ h16,
    const float* __restrict__ WA, const float* __restrict__ WB,
    unsigned short* __restrict__ hA16, unsigned short* __restrict__ hB16, int N)
{
  __shared__ float hl[8][DD];
  int tid = threadIdx.x;
  int ln = tid>>5, c = tid&31;
  int n = blockIdx.x*8 + ln;
  hl[ln][c] = (n<N)? h2f(h16[(long)n*DD+c]) : 0.f;
  __syncthreads();
  float a=0.f,b=0.f;
  #pragma unroll
  for (int k=0;k<DD;k++){
    float v = hl[ln][k];
    a = fmaf(v, WA[k*DD+c], a);
    b = fmaf(v, WB[k*DD+c], b);
  }
  if (n<N){ hA16[(long)n*DD+c]=f2h(a); hB16[(long)n*DD+c]=f2h(b); }
}

// MFMA edge kernel, SOFTWARE-PIPELINED (depth 1): one wave = 16 edges.
// D[m][n=edge]=Wf^T·e^T; f=leaky(D+hA[src]+hB[dst]+b); ebuf<-f; lbuf=exp(f·attn)
__global__ __launch_bounds__(256) void k_edge(
    unsigned short* __restrict__ ebuf,
    const unsigned short* __restrict__ hA16, const unsigned short* __restrict__ hB16,
    const unsigned* __restrict__ csr_sd,
    const float* __restrict__ Wf, const float* __restrict__ bvec,
    const float* __restrict__ attn,
    unsigned short* __restrict__ lbuf, int ntiles, int writef)
{
  int lane = threadIdx.x & 63;
  int wid = (blockIdx.x*256 + threadIdx.x) >> 6;
  int nw  = (gridDim.x*256) >> 6;
  int m = lane & 15, q = lane >> 4;
  half8 a0, a1;
  #pragma unroll
  for (int j=0;j<8;j++){
    a0[j] = (_Float16)Wf[(q*8+j)*DD + m];
    a1[j] = (_Float16)Wf[(q*8+j)*DD + 16 + m];
  }
  half2v bh[4], ah[4];
  #pragma unroll
  for (int j=0;j<2;j++){
    bh[j]   = __builtin_amdgcn_cvt_pkrtz(bvec[q*4+2*j],    bvec[q*4+2*j+1]);
    bh[2+j] = __builtin_amdgcn_cvt_pkrtz(bvec[16+q*4+2*j], bvec[16+q*4+2*j+1]);
    ah[j]   = __builtin_amdgcn_cvt_pkrtz(attn[q*4+2*j],    attn[q*4+2*j+1]);
    ah[2+j] = __builtin_amdgcn_cvt_pkrtz(attn[16+q*4+2*j], attn[16+q*4+2*j+1]);
  }
  const half2v c001 = {(__fp16)0.01f, (__fp16)0.01f};
  f32x4 zero = {0.f,0.f,0.f,0.f};
  // pipeline preamble: load tile wid fully
  half8 b_c = {};
  unsigned sd_c = 0;
  uint2 uA0_c={0,0}, uA1_c={0,0}, uB0_c={0,0}, uB1_c={0,0};
  if (wid < ntiles){
    long e0 = (long)wid*16 + m;
    sd_c = csr_sd[e0];
    b_c = *reinterpret_cast<const half8*>(ebuf + e0*DD + q*8);
    unsigned s = sd_c & 0xFFFFu, d = sd_c >> 16;
    const uint2* pA = reinterpret_cast<const uint2*>(hA16 + (long)s*DD);
    const uint2* pB = reinterpret_cast<const uint2*>(hB16 + (long)d*DD);
    uA0_c=pA[q]; uA1_c=pA[4+q]; uB0_c=pB[q]; uB1_c=pB[4+q];
  }
  for (int t = wid; t < ntiles; t += nw){
    int tn = t + nw;
    unsigned sd_n = 0; half8 b_n = {};
    if (tn < ntiles){
      long en = (long)tn*16 + m;
      sd_n = csr_sd[en];
      b_n = *reinterpret_cast<const half8*>(ebuf + en*DD + q*8);
    }
    f32x4 d0 = __builtin_amdgcn_mfma_f32_16x16x32_f16(a0, b_c, zero, 0,0,0);
    f32x4 d1 = __builtin_amdgcn_mfma_f32_16x16x32_f16(a1, b_c, zero, 0,0,0);
    uint2 uA0_n={0,0}, uA1_n={0,0}, uB0_n={0,0}, uB1_n={0,0};
    if (tn < ntiles){
      unsigned s = sd_n & 0xFFFFu, d = sd_n >> 16;
      const uint2* pA = reinterpret_cast<const uint2*>(hA16 + (long)s*DD);
      const uint2* pB = reinterpret_cast<const uint2*>(hB16 + (long)d*DD);
      uA0_n=pA[q]; uA1_n=pA[4+q]; uB0_n=pB[q]; uB1_n=pB[4+q];
    }
    long tbase = (long)t*16;
    long edge = tbase + m;
    half2v D[4];
    D[0] = __builtin_amdgcn_cvt_pkrtz(d0[0], d0[1]);
    D[1] = __builtin_amdgcn_cvt_pkrtz(d0[2], d0[3]);
    D[2] = __builtin_amdgcn_cvt_pkrtz(d1[0], d1[1]);
    D[3] = __builtin_amdgcn_cvt_pkrtz(d1[2], d1[3]);
    half2v A[4] = {u2h2(uA0_c.x), u2h2(uA0_c.y), u2h2(uA1_c.x), u2h2(uA1_c.y)};
    half2v B[4] = {u2h2(uB0_c.x), u2h2(uB0_c.y), u2h2(uB1_c.x), u2h2(uB1_c.y)};
    float l = 0.f;
    half2v F[4];
    #pragma unroll
    for (int j=0;j<4;j++){
      half2v f = D[j] + A[j] + B[j] + bh[j];             // v_pk_add_f16
      f = __builtin_elementwise_max(f, f*c001);          // leaky
      F[j] = f;
      l = __builtin_amdgcn_fdot2(f, ah[j], l, false);    // v_dot2_f32_f16
    }
    if (writef){
      uint2 w0, w1;
      w0.x = h22u(F[0]); w0.y = h22u(F[1]);
      w1.x = h22u(F[2]); w1.y = h22u(F[3]);
      *reinterpret_cast<uint2*>(ebuf + edge*DD + q*4) = w0;
      *reinterpret_cast<uint2*>(ebuf + edge*DD + 16 + q*4) = w1;
    }
    l += __shfl_xor(l, 16, 64);
    l += __shfl_xor(l, 32, 64);
    if (lane < 16){
      float lc = fminf(fmaxf(l, -15.f), 10.5f);
      lbuf[tbase + lane] = f2h(__expf(lc));   // max-free softmax weight
    }
    sd_c = sd_n; b_c = b_n;
    uA0_c=uA0_n; uA1_c=uA1_n; uB0_c=uB0_n; uB1_c=uB1_n;
  }
}

// per dst node (32 lanes, CSR): g16 = fp16( (sum ex*h16[src]) / (sum ex) )
// separate small kernel: 8 VGPR-class, high occupancy hides gather latency
__global__ __launch_bounds__(256) void k_aggr(
    const unsigned short* __restrict__ h16, const unsigned short* __restrict__ lbuf,
    const int* __restrict__ off, const unsigned* __restrict__ csr_sd,
    unsigned short* __restrict__ g16, int N)
{
  int tid=threadIdx.x;
  int n = blockIdx.x*8 + (tid>>5);
  int c = tid&31;
  if (n>=N) return;
  int o0 = off[n], o1 = off[n+1];
  float num=0.f, den=0.f;
  for (int i=o0;i<o1;i++){
    float ex = h2f(lbuf[i]);
    unsigned s = csr_sd[i] & 0xFFFFu;
    num = fmaf(ex, h2f(h16[(long)s*DD+c]), num);
    den += ex;
  }
  g16[(long)n*DD+c] = f2h((den>0.f) ? num/den : 0.f);
}

// fused proj + next-layer nodeAB: h16 = relu(g@Wnd); hA16 = h@WA; hB16 = h@WB
__global__ __launch_bounds__(256) void k_pnAB(
    const unsigned short* __restrict__ g16, const float* __restrict__ Wnd,
    const float* __restrict__ WA, const float* __restrict__ WB,
    unsigned short* __restrict__ h16,
    unsigned short* __restrict__ hA16, unsigned short* __restrict__ hB16, int N)
{
  __shared__ float gl[8][DD];
  __shared__ float tl[8][DD];
  int tid = threadIdx.x;
  int ln = tid>>5, c = tid&31;
  int n = blockIdx.x*8 + ln;
  gl[ln][c] = (n<N)? h2f(g16[(long)n*DD+c]) : 0.f;
  __syncthreads();
  float t=0.f;
  #pragma unroll
  for (int k=0;k<DD;k++) t = fmaf(gl[ln][k], Wnd[k*DD+c], t);
  t = fmaxf(t, 0.f);
  tl[ln][c] = t;
  __syncthreads();
  float a=0.f,b=0.f;
  #pragma unroll
  for (int k=0;k<DD;k++){
    float v = tl[ln][k];
    a = fmaf(v, WA[k*DD+c], a);
    b = fmaf(v, WB[k*DD+c], b);
  }
  if (n<N){
    h16[(long)n*DD+c]=f2h(t);
    hA16[(long)n*DD+c]=f2h(a);
    hB16[(long)n*DD+c]=f2h(b);
  }
}

// final proj: h(fp32) = relu(g @ Wnode)
__global__ __launch_bounds__(256) void k_proj(
    const unsigned short* __restrict__ g16, const float* __restrict__ W,
    float* __restrict__ h, int N)
{
  __shared__ float gl[8][DD];
  int tid = threadIdx.x;
  int ln = tid>>5, c = tid&31;
  int n = blockIdx.x*8 + ln;
  gl[ln][c] = (n<N)? h2f(g16[(long)n*DD+c]) : 0.f;
  __syncthreads();
  float a=0.f;
  #pragma unroll
  for (int k=0;k<DD;k++) a = fmaf(gl[ln][k], W[k*DD+c], a);
  if (n<N) h[(long)n*DD+c] = fmaxf(a, 0.f);
}

__global__ void k_keys(const float* __restrict__ h, unsigned long long* __restrict__ keys, int N){
  int n = blockIdx.x*blockDim.x + threadIdx.x;
  if (n>=N) return;
  const float4* p = reinterpret_cast<const float4*>(h + (long)n*DD);
  float m = -1e38f;
  #pragma unroll
  for (int j=0;j<8;j++){
    float4 v = p[j];
    m = fmaxf(m, fmaxf(fmaxf(v.x,v.y), fmaxf(v.z,v.w)));
  }
  keys[n] = ((unsigned long long)encf(m)<<32) | (unsigned)(~(unsigned)n);
}

// parallel top-8: per-thread register top-8 + 8-round block tournament (keys unique)
__global__ __launch_bounds__(256) void k_ptop(const unsigned long long* __restrict__ keys, int N,
                                              unsigned long long* __restrict__ outk){
  __shared__ unsigned long long red[256];
  int tid = threadIdx.x, b = blockIdx.x, nb = gridDim.x;
  int chunk = (N + nb - 1) / nb;
  int base = b*chunk, end = base+chunk; if (end>N) end=N;
  unsigned long long loc[TOPK];
  #pragma unroll
  for (int i=0;i<TOPK;i++) loc[i]=0ull;
  for (int i=base+tid; i<end; i+=256){
    unsigned long long k = keys[i];
    if (k > loc[TOPK-1]){
      int j = TOPK-1;
      while (j>0 && loc[j-1]<k){ loc[j]=loc[j-1]; j--; }
      loc[j]=k;
    }
  }
  for (int r=0; r<TOPK; r++){
    red[tid] = loc[0];
    __syncthreads();
    for (int s=128; s>0; s>>=1){
      if (tid<s && red[tid+s]>red[tid]) red[tid]=red[tid+s];
      __syncthreads();
    }
    unsigned long long w = red[0];
    if (tid==0) outk[b*TOPK + r] = w;
    if (loc[0]==w){
      #pragma unroll
      for (int j=0;j<TOPK-1;j++) loc[j]=loc[j+1];
      loc[TOPK-1]=0ull;
    }
    __syncthreads();
  }
}

__global__ __launch_bounds__(256) void k_head(
    const float* __restrict__ h, const unsigned long long* __restrict__ sel,
    const float* __restrict__ Wlin, const float* __restrict__ blin,
    const float* __restrict__ W1, const float* __restrict__ b1,
    const float* __restrict__ W2, const float* __restrict__ b2,
    const float* __restrict__ Wc, const float* __restrict__ bc,
    float* __restrict__ out, int N)
{
  __shared__ float xs[TOPK][DD];
  __shared__ float y1[DD], y2[DD], y3[DD];
  int tid=threadIdx.x;
  int r=tid>>5, c=tid&31;
  unsigned node = ~(unsigned)(sel[r] & 0xFFFFFFFFull);
  if (node >= (unsigned)N) node = 0;
  xs[r][c] = h[(long)node*DD + c];
  __syncthreads();
  if (tid<TOPK){
    for (int i=1;i<DD;i++){
      float v=xs[tid][i]; int j=i-1;
      while (j>=0 && xs[tid][j]>v){ xs[tid][j+1]=xs[tid][j]; j--; }
      xs[tid][j+1]=v;
    }
  }
  __syncthreads();
  if (tid<DD){
    float a=blin[tid];
    for (int i=0;i<TOPK*DD;i++) a = fmaf(xs[i>>5][i&31], Wlin[i*DD+tid], a);
    y1[tid] = a>0.f? a : 0.f;
  }
  __syncthreads();
  if (tid<DD){
    float a=b1[tid];
    #pragma unroll
    for (int i=0;i<DD;i++) a = fmaf(y1[i], W1[i*DD+tid], a);
    y2[tid] = a>0.f? a : 0.f;
  }
  __syncthreads();
  if (tid<DD){
    float a=b2[tid];
    #pragma unroll
    for (int i=0;i<DD;i++) a = fmaf(y2[i], W2[i*DD+tid], a);
    y3[tid] = a>0.f? a : 0.f;
  }
  __syncthreads();
  if (tid<2){
    float a=bc[tid];
    #pragma unroll
    for (int i=0;i<DD;i++) a = fmaf(y3[i], Wc[i*2+tid], a);
    out[tid] = a;                       // fp32 output
  }
}

extern "C" void kernel_launch(void* const* d_in, const int* in_sizes, int n_in,
                              void* d_out, int out_size, void* d_ws, size_t ws_size,
                              hipStream_t stream) {
  const int N = in_sizes[0];
  const int E = in_sizes[1];
  const float* tok_emb   = (const float*)d_in[4];
  const float* e_tok_emb = (const float*)d_in[5];
  const float* W_ni  = (const float*)d_in[6];
  const float* W_nj  = (const float*)d_in[7];
  const float* W_fij = (const float*)d_in[8];
  const float* b_e   = (const float*)d_in[9];
  const float* attn  = (const float*)d_in[10];
  const float* W_nd  = (const float*)d_in[11];

  char* p = (char*)d_ws;
  auto alloc = [&](size_t bytes)->char* {
    char* r = p; p += (bytes + 255) & ~(size_t)255; return r;
  };
  // ~131.5 MB total (sde8 aliases h+g16+lbuf, all dead at setup)
  int* iflag = (int*)alloc(256);
  unsigned long long* sel = (unsigned long long*)alloc(256);
  unsigned long long* cand = (unsigned long long*)alloc(256*TOPK*8);
  int* csroff = (int*)alloc((size_t)(N+1)*4);
  unsigned* csr_sd = (unsigned*)alloc((size_t)(E+16)*4);
  float* h = (float*)alloc((size_t)N*DD*4);                     // fp32, final only
  unsigned short* g16  = (unsigned short*)alloc((size_t)N*DD*2);
  unsigned short* lbuf = (unsigned short*)alloc((size_t)(E+16)*2);
  unsigned short* h16  = (unsigned short*)alloc((size_t)N*DD*2);
  unsigned short* hA16 = (unsigned short*)alloc((size_t)N*DD*2);
  unsigned short* hB16 = (unsigned short*)alloc((size_t)N*DD*2);
  unsigned short* ebuf = (unsigned short*)alloc((size_t)(E+16)*DD*2);
  int* cnt    = (int*)hA16;                       // alias: dead until nodeAB
  int* cursor = (int*)hB16;                       // alias: dead until nodeAB
  uint2* sde8 = (uint2*)h;                        // alias: spans h+g16+lbuf (12.8 MB)
  unsigned long long* keys = (unsigned long long*)lbuf;  // alias: lbuf dead after last aggr

  hipLaunchKernelGGL(k_detect, dim3(1), dim3(64), 0, stream, (const int*)d_in[2], iflag);
  hipLaunchKernelGGL(k_zero, dim3((N+255)/256), dim3(256), 0, stream, cnt, cursor, N);
  {
    long total = (long)N*8 + E;
    hipLaunchKernelGGL(k_init, dim3((int)((total+255)/256)), dim3(256), 0, stream,
                       d_in[0], d_in[3], tok_emb, h16, cnt, iflag, N, E);
  }
  hipLaunchKernelGGL(k_scan, dim3(1), dim3(1024), 0, stream, cnt, csroff, N, E);
  hipLaunchKernelGGL(k_scatter, dim3((E+255)/256), dim3(256), 0, stream,
                     d_in[2], d_in[3], csroff, cursor, sde8, iflag, E);
  hipLaunchKernelGGL(k_fill, dim3((int)(((long)E*4+255)/256)), dim3(256), 0, stream,
                     sde8, d_in[1], e_tok_emb, csr_sd, ebuf, iflag, E);

  int nb_node = (N+7)/8;
  int ntiles = (E+15)/16;
  hipLaunchKernelGGL(k_nodeAB, dim3(nb_node), dim3(256), 0, stream,
                     h16, W_ni, W_nj, hA16, hB16, N);
  for (int l=0; l<NLAYERS; l++){
    const float* Wf  = W_fij + (size_t)l*DD*DD;
    const float* bl  = b_e   + (size_t)l*DD;
    const float* at  = attn  + (size_t)l*DD;
    const float* Wnd = W_nd  + (size_t)l*DD*DD;
    hipLaunchKernelGGL(k_edge, dim3(2048), dim3(256), 0, stream,
                       ebuf, hA16, hB16, csr_sd, Wf, bl, at, lbuf, ntiles,
                       (l < NLAYERS-1) ? 1 : 0);
    hipLaunchKernelGGL(k_aggr, dim3(nb_node), dim3(256), 0, stream,
                       h16, lbuf, csroff, csr_sd, g16, N);
    if (l < NLAYERS-1){
      const float* WnA = W_ni + (size_t)(l+1)*DD*DD;
      const float* WnB = W_nj + (size_t)(l+1)*DD*DD;
      hipLaunchKernelGGL(k_pnAB, dim3(nb_node), dim3(256), 0, stream,
                         g16, Wnd, WnA, WnB, h16, hA16, hB16, N);
    } else {
      hipLaunchKernelGGL(k_proj, dim3(nb_node), dim3(256), 0, stream,
                         g16, Wnd, h, N);
    }
  }

  hipLaunchKernelGGL(k_keys, dim3((N+255)/256), dim3(256), 0, stream, h, keys, N);
  hipLaunchKernelGGL(k_ptop, dim3(256), dim3(256), 0, stream, keys, N, cand);
  hipLaunchKernelGGL(k_ptop, dim3(1), dim3(256), 0, stream, cand, 256*TOPK, sel);
  hipLaunchKernelGGL(k_head, dim3(1), dim3(256), 0, stream,
                     h, sel,
                     (const float*)d_in[12], (const float*)d_in[13],
                     (const float*)d_in[14], (const float*)d_in[15],
                     (const float*)d_in[16], (const float*)d_in[17],
                     (const float*)d_in[18], (const float*)d_in[19],
                     (float*)d_out, N);
}